// Round 10
// baseline (260.491 us; speedup 1.0000x reference)
//
#include <hip/hip_runtime.h>
#include <math.h>

// GCN 2-layer, algebraically fused, ATOMIC-FREE (global):
//   agg_x[d] = dinv[d]*(sum_{s in N(d)} xp[s] + xp[d]),  xp = dinv*x
//   h = relu(agg_x@W1+b1); g = h@W2; gp = dinv*g
//   out = log_softmax(dinv[d]*(sum gp[s] + gp[d]) + b2)
//
// R9: REVERT to R5 config (best measured: 186.8us) + instrumentation:
//     two extra k_agg_slice dispatches into scratch partial2. dur delta vs
//     186.8 = 2*t_agg (direct measurement; top-5 profile is blinded by
//     harness fills at 44us). R6/R7/R8 micro-theories all predicted -15..-30
//     and delivered ~0 -> measure before editing further.

#define BLK 256
#define NTILE 512
#define EPTMAX 6400        // >= runtime ept (6252), multiple of 4
#define MAXB 512           // >= nbkt = 391
#define NS 8               // slices per bucket in Phase B

// ---------- Phase A ----------

__global__ void k_hist(const int* __restrict__ dst, int* __restrict__ table,
                       int e, int ept, int nbkt) {
    __shared__ int h[MAXB];
    int tile = blockIdx.x;
    for (int i = threadIdx.x; i < MAXB; i += BLK) h[i] = 0;
    __syncthreads();
    int lo = tile * ept;
    int hi = min(lo + ept, e);
    for (int i = lo + 4 * threadIdx.x; i < hi; i += 4 * BLK) {
        int4 d4 = *(const int4*)(dst + i);
        atomicAdd(&h[d4.x >> 8], 1);
        atomicAdd(&h[d4.y >> 8], 1);
        atomicAdd(&h[d4.z >> 8], 1);
        atomicAdd(&h[d4.w >> 8], 1);
    }
    __syncthreads();
    for (int i = threadIdx.x; i < nbkt; i += BLK)
        table[tile * nbkt + i] = h[i];
}

__global__ void k_scan_col(int* __restrict__ table, int* __restrict__ tot, int nbkt) {
    __shared__ int wsum[NTILE / 64];
    int b = blockIdx.x;
    int t = threadIdx.x;
    int v = table[t * nbkt + b];
    int x = v;
    int lane = t & 63;
#pragma unroll
    for (int ofs = 1; ofs < 64; ofs <<= 1) {
        int y = __shfl_up(x, ofs, 64);
        if (lane >= ofs) x += y;
    }
    if (lane == 63) wsum[t >> 6] = x;
    __syncthreads();
    if (t < NTILE / 64) {
        int s = wsum[t];
        int w = s;
#pragma unroll
        for (int ofs = 1; ofs < NTILE / 64; ofs <<= 1) {
            int y = __shfl_up(w, ofs, 64);
            if (t >= ofs) w += y;
        }
        wsum[t] = w - s;
    }
    __syncthreads();
    int incl = x + wsum[t >> 6];
    table[t * nbkt + b] = incl - v;
    if (t == NTILE - 1) tot[b] = incl;
}

__global__ void k_scan_tot(const int* __restrict__ tot, int* __restrict__ bkt_off, int nbkt) {
    __shared__ int wsum[MAXB / 64];
    int t = threadIdx.x;               // MAXB threads
    int v = (t < nbkt) ? tot[t] : 0;
    int x = v;
    int lane = t & 63;
#pragma unroll
    for (int ofs = 1; ofs < 64; ofs <<= 1) {
        int y = __shfl_up(x, ofs, 64);
        if (lane >= ofs) x += y;
    }
    if (lane == 63) wsum[t >> 6] = x;
    __syncthreads();
    if (t < MAXB / 64) {
        int s = wsum[t];
        int w = s;
#pragma unroll
        for (int ofs = 1; ofs < MAXB / 64; ofs <<= 1) {
            int y = __shfl_up(w, ofs, 64);
            if (t >= ofs) w += y;
        }
        wsum[t] = w - s;
    }
    __syncthreads();
    int incl = x + wsum[t >> 6];
    if (t < nbkt) bkt_off[t] = incl - v;
    if (t == nbkt - 1) bkt_off[nbkt] = incl;
}

__global__ void k_scatter(const int* __restrict__ src, const int* __restrict__ dst,
                          const int* __restrict__ table, const int* __restrict__ tot,
                          const int* __restrict__ bkt_off, unsigned* __restrict__ sorted,
                          int e, int ept, int nbkt) {
    __shared__ int cur[MAXB];
    __shared__ int base2[MAXB];
    __shared__ unsigned stage[EPTMAX];
    __shared__ unsigned short stage_b[EPTMAX];
    __shared__ int wpart[BLK / 64];
    int tile = blockIdx.x;
    int t = threadIdx.x;
    int lo = tile * ept;
    int hi = min(lo + ept, e);
    int total = hi - lo;

    int b0 = 2 * t, b1 = 2 * t + 1;
    int c0 = 0, c1 = 0, g0 = 0, g1 = 0;
    if (b0 < nbkt) {
        int base = table[tile * nbkt + b0];
        int next = (tile < NTILE - 1) ? table[(tile + 1) * nbkt + b0] : tot[b0];
        c0 = next - base;
        g0 = bkt_off[b0] + base;
    }
    if (b1 < nbkt) {
        int base = table[tile * nbkt + b1];
        int next = (tile < NTILE - 1) ? table[(tile + 1) * nbkt + b1] : tot[b1];
        c1 = next - base;
        g1 = bkt_off[b1] + base;
    }
    int p = c0 + c1;
    int x = p;
    int lane = t & 63;
#pragma unroll
    for (int ofs = 1; ofs < 64; ofs <<= 1) {
        int y = __shfl_up(x, ofs, 64);
        if (lane >= ofs) x += y;
    }
    if (lane == 63) wpart[t >> 6] = x;
    __syncthreads();
    if (t < BLK / 64) {
        int s = wpart[t];
        int w = s;
#pragma unroll
        for (int ofs = 1; ofs < BLK / 64; ofs <<= 1) {
            int y = __shfl_up(w, ofs, 64);
            if (t >= ofs) w += y;
        }
        wpart[t] = w - s;
    }
    __syncthreads();
    int E = x + wpart[t >> 6] - p;
    cur[b0] = E;
    cur[b1] = E + c0;
    if (b0 < nbkt) base2[b0] = g0 - E;
    if (b1 < nbkt) base2[b1] = g1 - (E + c0);
    __syncthreads();

    for (int i = lo + 4 * t; i < hi; i += 4 * BLK) {
        int4 s4 = *(const int4*)(src + i);
        int4 d4 = *(const int4*)(dst + i);
        int b, pos;
        b = d4.x >> 8; pos = atomicAdd(&cur[b], 1);
        stage[pos] = (unsigned)s4.x | ((unsigned)(d4.x & 255) << 17); stage_b[pos] = (unsigned short)b;
        b = d4.y >> 8; pos = atomicAdd(&cur[b], 1);
        stage[pos] = (unsigned)s4.y | ((unsigned)(d4.y & 255) << 17); stage_b[pos] = (unsigned short)b;
        b = d4.z >> 8; pos = atomicAdd(&cur[b], 1);
        stage[pos] = (unsigned)s4.z | ((unsigned)(d4.z & 255) << 17); stage_b[pos] = (unsigned short)b;
        b = d4.w >> 8; pos = atomicAdd(&cur[b], 1);
        stage[pos] = (unsigned)s4.w | ((unsigned)(d4.w & 255) << 17); stage_b[pos] = (unsigned short)b;
    }
    __syncthreads();
    for (int j = t; j < total; j += BLK) {
        int b = stage_b[j];
        sorted[base2[b] + j] = stage[j];
    }
}

// ---------- degree ----------

__global__ void k_deg_slice(const unsigned* __restrict__ sorted, const int* __restrict__ bkt_off,
                            int* __restrict__ pdeg) {
    __shared__ int cnt[256];
    int b = blockIdx.x, s = blockIdx.y;
    cnt[threadIdx.x] = 0;
    __syncthreads();
    int lo = bkt_off[b], hi = bkt_off[b + 1];
    int len = hi - lo;
    int slo = lo + (int)((long long)len * s / NS);
    int shi = lo + (int)((long long)len * (s + 1) / NS);
    for (int i = slo + threadIdx.x; i < shi; i += BLK)
        atomicAdd(&cnt[sorted[i] >> 17], 1);
    __syncthreads();
    pdeg[(b * NS + s) * 256 + threadIdx.x] = cnt[threadIdx.x];
}

__global__ void k_dinv_merge(const int* __restrict__ pdeg, const float* __restrict__ x,
                             float* __restrict__ dinv, float* __restrict__ xp, int n) {
    int i = blockIdx.x * BLK + threadIdx.x;
    if (i >= n) return;
    int b = i >> 8, t = i & 255;
    int deg = 1;  // self loop
#pragma unroll
    for (int s = 0; s < NS; ++s) deg += pdeg[(b * NS + s) * 256 + t];
    float d = rsqrtf((float)deg);
    dinv[i] = d;
    float2 xv = ((const float2*)x)[i];
    ((float2*)xp)[i] = make_float2(d * xv.x, d * xv.y);
}

// ---------- Phase B ----------

__global__ void k_agg_slice(const unsigned* __restrict__ sorted, const int* __restrict__ bkt_off,
                            const float* __restrict__ featp, float* __restrict__ partial) {
    __shared__ float acc[512];
    int b = blockIdx.x, s = blockIdx.y;
    acc[threadIdx.x] = 0.f;
    acc[threadIdx.x + 256] = 0.f;
    __syncthreads();
    int lo = bkt_off[b], hi = bkt_off[b + 1];
    int len = hi - lo;
    int slo = lo + (int)((long long)len * s / NS);
    int shi = lo + (int)((long long)len * (s + 1) / NS);
    for (int i = slo + threadIdx.x; i < shi; i += BLK) {
        unsigned p = sorted[i];
        float2 f = ((const float2*)featp)[p & 0x1FFFFu];
        int dl = (int)(p >> 17);
        atomicAdd(&acc[2 * dl],     f.x);
        atomicAdd(&acc[2 * dl + 1], f.y);
    }
    __syncthreads();
    float2* out = (float2*)&partial[(size_t)(b * NS + s) * 512];
    out[threadIdx.x] = make_float2(acc[2 * threadIdx.x], acc[2 * threadIdx.x + 1]);
}

__global__ void k_mlp_merge(const float* __restrict__ partial, const float* __restrict__ dinv,
                            const float* __restrict__ xp,
                            const float* __restrict__ W1, const float* __restrict__ b1,
                            const float* __restrict__ W2, float* __restrict__ gp, int n) {
    int i = blockIdx.x * BLK + threadIdx.x;
    if (i >= n) return;
    int b = i >> 8, t = i & 255;
    float2 xv = ((const float2*)xp)[i];
    float ax = xv.x, ay = xv.y;
#pragma unroll
    for (int s = 0; s < NS; ++s) {
        float2 p = ((const float2*)&partial[(size_t)(b * NS + s) * 512])[t];
        ax += p.x; ay += p.y;
    }
    float d = dinv[i];
    ax *= d; ay *= d;
    float g0 = 0.f, g1 = 0.f;
#pragma unroll
    for (int f = 0; f < 16; ++f) {
        float h = fmaf(ax, W1[f], fmaf(ay, W1[16 + f], b1[f]));
        h = fmaxf(h, 0.0f);
        g0 = fmaf(h, W2[2 * f + 0], g0);
        g1 = fmaf(h, W2[2 * f + 1], g1);
    }
    ((float2*)gp)[i] = make_float2(d * g0, d * g1);
}

__global__ void k_final(const float* __restrict__ partial, const float* __restrict__ dinv,
                        const float* __restrict__ gp, const float* __restrict__ b2,
                        float* __restrict__ out, int n) {
    int i = blockIdx.x * BLK + threadIdx.x;
    if (i >= n) return;
    int b = i >> 8, t = i & 255;
    float2 gv = ((const float2*)gp)[i];
    float ax = gv.x, ay = gv.y;
#pragma unroll
    for (int s = 0; s < NS; ++s) {
        float2 p = ((const float2*)&partial[(size_t)(b * NS + s) * 512])[t];
        ax += p.x; ay += p.y;
    }
    float d = dinv[i];
    float z0 = d * ax + b2[0];
    float z1 = d * ay + b2[1];
    float m = fmaxf(z0, z1);
    float lse = m + logf(expf(z0 - m) + expf(z1 - m));
    ((float2*)out)[i] = make_float2(z0 - lse, z1 - lse);
}

extern "C" void kernel_launch(void* const* d_in, const int* in_sizes, int n_in,
                              void* d_out, int out_size, void* d_ws, size_t ws_size,
                              hipStream_t stream) {
    const float* x  = (const float*)d_in[0];   // [n,2]
    const int*   ei = (const int*)d_in[1];     // [2,e]: row0=src, row1=dst
    const float* W1 = (const float*)d_in[2];   // [2,16]
    const float* b1 = (const float*)d_in[3];   // [16]
    const float* W2 = (const float*)d_in[4];   // [16,2]
    const float* b2 = (const float*)d_in[5];   // [2]
    float* out = (float*)d_out;                // [n,2]

    const int n = in_sizes[0] / 2;             // 100000
    const int e = in_sizes[1] / 2;             // 3200000
    const int* src = ei;
    const int* dst = ei + e;

    const int nbkt = (n + 255) >> 8;           // 391
    int ept = (((e + NTILE - 1) / NTILE) + 3) & ~3;   // 6252

    char* base = (char*)d_ws;
    size_t off = 0;
    auto take = [&](size_t bytes) { char* p = base + off; off += (bytes + 255) & ~(size_t)255; return p; };
    unsigned* sorted   = (unsigned*)take((size_t)e * 4);                   // 12.8 MB
    int*      table    = (int*)take((size_t)NTILE * nbkt * 4);             // 0.8 MB
    int*      tot      = (int*)take((size_t)MAXB * 4);
    int*      bkt_off  = (int*)take((size_t)(MAXB + 1) * 4);
    float*    partial  = (float*)take((size_t)nbkt * NS * 512 * 4);        // 6.4 MB (aliases pdeg)
    int*      pdeg     = (int*)partial;
    float*    dinv     = (float*)take((size_t)n * 4);
    float*    xp       = (float*)take((size_t)n * 8);
    float*    gp       = (float*)take((size_t)n * 8);
    float*    partial2 = (float*)take((size_t)nbkt * NS * 512 * 4);        // scratch (instrumentation)

    const int gn = (n + BLK - 1) / BLK;
    dim3 gslice(nbkt, NS);

    k_hist      <<<NTILE, BLK, 0, stream>>>(dst, table, e, ept, nbkt);
    k_scan_col  <<<nbkt, NTILE, 0, stream>>>(table, tot, nbkt);
    k_scan_tot  <<<1, MAXB, 0, stream>>>(tot, bkt_off, nbkt);
    k_scatter   <<<NTILE, BLK, 0, stream>>>(src, dst, table, tot, bkt_off, sorted, e, ept, nbkt);
    k_deg_slice <<<gslice, BLK, 0, stream>>>(sorted, bkt_off, pdeg);
    k_dinv_merge<<<gn, BLK, 0, stream>>>(pdeg, x, dinv, xp, n);
    k_agg_slice <<<gslice, BLK, 0, stream>>>(sorted, bkt_off, xp, partial);    // layer 1 (real)
    // ---- instrumentation: two duplicate agg passes into scratch; dur delta = 2*t_agg ----
    k_agg_slice <<<gslice, BLK, 0, stream>>>(sorted, bkt_off, xp, partial2);   // dup 1
    k_agg_slice <<<gslice, BLK, 0, stream>>>(sorted, bkt_off, xp, partial2);   // dup 2
    // -----------------------------------------------------------------------------------
    k_mlp_merge <<<gn, BLK, 0, stream>>>(partial, dinv, xp, W1, b1, W2, gp, n);
    k_agg_slice <<<gslice, BLK, 0, stream>>>(sorted, bkt_off, gp, partial);    // layer 2 (real)
    k_final     <<<gn, BLK, 0, stream>>>(partial, dinv, gp, b2, out, n);
}

// Round 11
// 161.464 us; speedup vs baseline: 1.6133x; 1.6133x over previous
//
#include <hip/hip_runtime.h>
#include <math.h>

// GCN 2-layer, algebraically fused:
//   agg_x[d] = dinv[d]*(sum_{s in N(d)} xp[s] + xp[d]),  xp = dinv*x
//   h = relu(agg_x@W1+b1); g = h@W2; gp = dinv*g
//   out = log_softmax(dinv[d]*(sum gp[s] + gp[d]) + b2)
//
// R5 base (186.8us). R9 instrumentation measured t_agg = 37us/pass (74us of
// 187 total) -> edge passes dominate. R10: second-level counting sort inside
// each bucket (k_bsort) makes records NODE-contiguous; degree+dinv+xp fall out
// of its histogram (absorbs deg_slice + dinv_merge). Both agg passes become
// atomic-free segmented sums: 4 threads/node over a contiguous run, shfl_xor
// quad-reduce, fused epilogues (agg2 includes bias+log_softmax -> kills
// k_final and all partial-buffer traffic). 10 -> 8 dispatches.

#define BLK 256
#define NTILE 512
#define EPTMAX 6400        // >= runtime ept (6252), multiple of 4
#define MAXB 512           // >= nbkt = 391

// ---------- Phase A (unchanged from R5) ----------

__global__ void k_hist(const int* __restrict__ dst, int* __restrict__ table,
                       int e, int ept, int nbkt) {
    __shared__ int h[MAXB];
    int tile = blockIdx.x;
    for (int i = threadIdx.x; i < MAXB; i += BLK) h[i] = 0;
    __syncthreads();
    int lo = tile * ept;
    int hi = min(lo + ept, e);
    for (int i = lo + 4 * threadIdx.x; i < hi; i += 4 * BLK) {
        int4 d4 = *(const int4*)(dst + i);
        atomicAdd(&h[d4.x >> 8], 1);
        atomicAdd(&h[d4.y >> 8], 1);
        atomicAdd(&h[d4.z >> 8], 1);
        atomicAdd(&h[d4.w >> 8], 1);
    }
    __syncthreads();
    for (int i = threadIdx.x; i < nbkt; i += BLK)
        table[tile * nbkt + i] = h[i];
}

__global__ void k_scan_col(int* __restrict__ table, int* __restrict__ tot, int nbkt) {
    __shared__ int wsum[NTILE / 64];
    int b = blockIdx.x;
    int t = threadIdx.x;
    int v = table[t * nbkt + b];
    int x = v;
    int lane = t & 63;
#pragma unroll
    for (int ofs = 1; ofs < 64; ofs <<= 1) {
        int y = __shfl_up(x, ofs, 64);
        if (lane >= ofs) x += y;
    }
    if (lane == 63) wsum[t >> 6] = x;
    __syncthreads();
    if (t < NTILE / 64) {
        int s = wsum[t];
        int w = s;
#pragma unroll
        for (int ofs = 1; ofs < NTILE / 64; ofs <<= 1) {
            int y = __shfl_up(w, ofs, 64);
            if (t >= ofs) w += y;
        }
        wsum[t] = w - s;
    }
    __syncthreads();
    int incl = x + wsum[t >> 6];
    table[t * nbkt + b] = incl - v;
    if (t == NTILE - 1) tot[b] = incl;
}

__global__ void k_scan_tot(const int* __restrict__ tot, int* __restrict__ bkt_off, int nbkt) {
    __shared__ int wsum[MAXB / 64];
    int t = threadIdx.x;               // MAXB threads
    int v = (t < nbkt) ? tot[t] : 0;
    int x = v;
    int lane = t & 63;
#pragma unroll
    for (int ofs = 1; ofs < 64; ofs <<= 1) {
        int y = __shfl_up(x, ofs, 64);
        if (lane >= ofs) x += y;
    }
    if (lane == 63) wsum[t >> 6] = x;
    __syncthreads();
    if (t < MAXB / 64) {
        int s = wsum[t];
        int w = s;
#pragma unroll
        for (int ofs = 1; ofs < MAXB / 64; ofs <<= 1) {
            int y = __shfl_up(w, ofs, 64);
            if (t >= ofs) w += y;
        }
        wsum[t] = w - s;
    }
    __syncthreads();
    int incl = x + wsum[t >> 6];
    if (t < nbkt) bkt_off[t] = incl - v;
    if (t == nbkt - 1) bkt_off[nbkt] = incl;
}

__global__ void k_scatter(const int* __restrict__ src, const int* __restrict__ dst,
                          const int* __restrict__ table, const int* __restrict__ tot,
                          const int* __restrict__ bkt_off, unsigned* __restrict__ sorted,
                          int e, int ept, int nbkt) {
    __shared__ int cur[MAXB];
    __shared__ int base2[MAXB];
    __shared__ unsigned stage[EPTMAX];
    __shared__ unsigned short stage_b[EPTMAX];
    __shared__ int wpart[BLK / 64];
    int tile = blockIdx.x;
    int t = threadIdx.x;
    int lo = tile * ept;
    int hi = min(lo + ept, e);
    int total = hi - lo;

    int b0 = 2 * t, b1 = 2 * t + 1;
    int c0 = 0, c1 = 0, g0 = 0, g1 = 0;
    if (b0 < nbkt) {
        int base = table[tile * nbkt + b0];
        int next = (tile < NTILE - 1) ? table[(tile + 1) * nbkt + b0] : tot[b0];
        c0 = next - base;
        g0 = bkt_off[b0] + base;
    }
    if (b1 < nbkt) {
        int base = table[tile * nbkt + b1];
        int next = (tile < NTILE - 1) ? table[(tile + 1) * nbkt + b1] : tot[b1];
        c1 = next - base;
        g1 = bkt_off[b1] + base;
    }
    int p = c0 + c1;
    int x = p;
    int lane = t & 63;
#pragma unroll
    for (int ofs = 1; ofs < 64; ofs <<= 1) {
        int y = __shfl_up(x, ofs, 64);
        if (lane >= ofs) x += y;
    }
    if (lane == 63) wpart[t >> 6] = x;
    __syncthreads();
    if (t < BLK / 64) {
        int s = wpart[t];
        int w = s;
#pragma unroll
        for (int ofs = 1; ofs < BLK / 64; ofs <<= 1) {
            int y = __shfl_up(w, ofs, 64);
            if (t >= ofs) w += y;
        }
        wpart[t] = w - s;
    }
    __syncthreads();
    int E = x + wpart[t >> 6] - p;
    cur[b0] = E;
    cur[b1] = E + c0;
    if (b0 < nbkt) base2[b0] = g0 - E;
    if (b1 < nbkt) base2[b1] = g1 - (E + c0);
    __syncthreads();

    for (int i = lo + 4 * t; i < hi; i += 4 * BLK) {
        int4 s4 = *(const int4*)(src + i);
        int4 d4 = *(const int4*)(dst + i);
        int b, pos;
        b = d4.x >> 8; pos = atomicAdd(&cur[b], 1);
        stage[pos] = (unsigned)s4.x | ((unsigned)(d4.x & 255) << 17); stage_b[pos] = (unsigned short)b;
        b = d4.y >> 8; pos = atomicAdd(&cur[b], 1);
        stage[pos] = (unsigned)s4.y | ((unsigned)(d4.y & 255) << 17); stage_b[pos] = (unsigned short)b;
        b = d4.z >> 8; pos = atomicAdd(&cur[b], 1);
        stage[pos] = (unsigned)s4.z | ((unsigned)(d4.z & 255) << 17); stage_b[pos] = (unsigned short)b;
        b = d4.w >> 8; pos = atomicAdd(&cur[b], 1);
        stage[pos] = (unsigned)s4.w | ((unsigned)(d4.w & 255) << 17); stage_b[pos] = (unsigned short)b;
    }
    __syncthreads();
    for (int j = t; j < total; j += BLK) {
        int b = stage_b[j];
        sorted[base2[b] + j] = stage[j];
    }
}

// ---------- R10: per-bucket node-sort + degree + dinv + xp ----------
// One 1024-thread block per bucket. Histogram over dl gives degree (-> dinv,
// xp) AND the node-local offsets (shuffle scan); second read scatters records
// into node-contiguous order. nodeoff[b*256+t] written for ALL t so the next
// bucket's first entry is the sentinel for the previous bucket's last node.
__global__ __launch_bounds__(1024) void k_bsort(
        const unsigned* __restrict__ sorted, const int* __restrict__ bkt_off,
        const float* __restrict__ x, float* __restrict__ dinv,
        float* __restrict__ xp, unsigned* __restrict__ nsorted,
        int* __restrict__ nodeoff, int n) {
    __shared__ int cnt[256];
    __shared__ int cur[256];
    __shared__ int wsum[16];
    int b = blockIdx.x, t = threadIdx.x;
    if (t < 256) cnt[t] = 0;
    __syncthreads();
    int lo = bkt_off[b], hi = bkt_off[b + 1];
    for (int i = lo + t; i < hi; i += 1024)
        atomicAdd(&cnt[sorted[i] >> 17], 1);
    __syncthreads();
    int c = (t < 256) ? cnt[t] : 0;
    // degree outputs
    int node = (b << 8) + t;
    if (t < 256 && node < n) {
        float d = rsqrtf((float)c + 1.0f);   // +1 self loop
        dinv[node] = d;
        float2 xv = ((const float2*)x)[node];
        ((float2*)xp)[node] = make_float2(d * xv.x, d * xv.y);
    }
    // exclusive scan of cnt (first 4 waves carry real data)
    int xsc = c;
    int lane = t & 63;
#pragma unroll
    for (int ofs = 1; ofs < 64; ofs <<= 1) {
        int y = __shfl_up(xsc, ofs, 64);
        if (lane >= ofs) xsc += y;
    }
    if (lane == 63) wsum[t >> 6] = xsc;
    __syncthreads();
    if (t < 4) {
        int s = wsum[t];
        int w = s;
#pragma unroll
        for (int ofs = 1; ofs < 4; ofs <<= 1) {
            int y = __shfl_up(w, ofs, 64);
            if (t >= ofs) w += y;
        }
        wsum[t] = w - s;
    }
    __syncthreads();
    if (t < 256) {
        int excl = xsc + wsum[t >> 6] - c;
        cur[t] = excl;
        nodeoff[(b << 8) + t] = lo + excl;
    }
    __syncthreads();
    // scatter to node-contiguous order (writes land within this bucket's
    // 32KB region -> lines fully dirtied while hot in L2)
    for (int i = lo + t; i < hi; i += 1024) {
        unsigned p = sorted[i];
        int pos = atomicAdd(&cur[p >> 17], 1);
        nsorted[lo + pos] = p & 0x1FFFFu;
    }
}

// ---------- Phase B: atomic-free segmented sums, 4 threads/node ----------

// layer 1: aggx[d] = dinv[d]*(sum xp[s] + xp[d])
__global__ void k_agg1(const unsigned* __restrict__ nsorted, const int* __restrict__ nodeoff,
                       const float* __restrict__ xp, const float* __restrict__ dinv,
                       float* __restrict__ aggx, int n) {
    int t = threadIdx.x;
    int nd = (blockIdx.x << 8) + (blockIdx.y << 6) + (t >> 2);
    int q = t & 3;
    if (nd >= n) return;
    int start = nodeoff[nd], end = nodeoff[nd + 1];
    float sx = 0.f, sy = 0.f;
    for (int i = start + q; i < end; i += 4) {
        float2 f = ((const float2*)xp)[nsorted[i]];
        sx += f.x; sy += f.y;
    }
    sx += __shfl_xor(sx, 1); sy += __shfl_xor(sy, 1);
    sx += __shfl_xor(sx, 2); sy += __shfl_xor(sy, 2);
    if (q == 0) {
        float d = dinv[nd];
        float2 xv = ((const float2*)xp)[nd];
        ((float2*)aggx)[nd] = make_float2(d * (sx + xv.x), d * (sy + xv.y));
    }
}

// per node: h = relu(aggx@W1+b1); gp = dinv * (h@W2)
__global__ void k_mlp(const float* __restrict__ aggx, const float* __restrict__ dinv,
                      const float* __restrict__ W1, const float* __restrict__ b1,
                      const float* __restrict__ W2, float* __restrict__ gp, int n) {
    int i = blockIdx.x * BLK + threadIdx.x;
    if (i >= n) return;
    float2 a = ((const float2*)aggx)[i];
    float g0 = 0.f, g1 = 0.f;
#pragma unroll
    for (int f = 0; f < 16; ++f) {
        float h = fmaf(a.x, W1[f], fmaf(a.y, W1[16 + f], b1[f]));
        h = fmaxf(h, 0.0f);
        g0 = fmaf(h, W2[2 * f + 0], g0);
        g1 = fmaf(h, W2[2 * f + 1], g1);
    }
    float d = dinv[i];
    ((float2*)gp)[i] = make_float2(d * g0, d * g1);
}

// layer 2 + bias + log_softmax, fused epilogue
__global__ void k_agg2(const unsigned* __restrict__ nsorted, const int* __restrict__ nodeoff,
                       const float* __restrict__ gp, const float* __restrict__ dinv,
                       const float* __restrict__ b2, float* __restrict__ out, int n) {
    int t = threadIdx.x;
    int nd = (blockIdx.x << 8) + (blockIdx.y << 6) + (t >> 2);
    int q = t & 3;
    if (nd >= n) return;
    int start = nodeoff[nd], end = nodeoff[nd + 1];
    float sx = 0.f, sy = 0.f;
    for (int i = start + q; i < end; i += 4) {
        float2 f = ((const float2*)gp)[nsorted[i]];
        sx += f.x; sy += f.y;
    }
    sx += __shfl_xor(sx, 1); sy += __shfl_xor(sy, 1);
    sx += __shfl_xor(sx, 2); sy += __shfl_xor(sy, 2);
    if (q == 0) {
        float d = dinv[nd];
        float2 gv = ((const float2*)gp)[nd];
        float z0 = d * (sx + gv.x) + b2[0];
        float z1 = d * (sy + gv.y) + b2[1];
        float m = fmaxf(z0, z1);
        float lse = m + logf(expf(z0 - m) + expf(z1 - m));
        ((float2*)out)[nd] = make_float2(z0 - lse, z1 - lse);
    }
}

extern "C" void kernel_launch(void* const* d_in, const int* in_sizes, int n_in,
                              void* d_out, int out_size, void* d_ws, size_t ws_size,
                              hipStream_t stream) {
    const float* x  = (const float*)d_in[0];   // [n,2]
    const int*   ei = (const int*)d_in[1];     // [2,e]: row0=src, row1=dst
    const float* W1 = (const float*)d_in[2];   // [2,16]
    const float* b1 = (const float*)d_in[3];   // [16]
    const float* W2 = (const float*)d_in[4];   // [16,2]
    const float* b2 = (const float*)d_in[5];   // [2]
    float* out = (float*)d_out;                // [n,2]

    const int n = in_sizes[0] / 2;             // 100000
    const int e = in_sizes[1] / 2;             // 3200000
    const int* src = ei;
    const int* dst = ei + e;

    const int nbkt = (n + 255) >> 8;           // 391
    int ept = (((e + NTILE - 1) / NTILE) + 3) & ~3;   // 6252

    char* base = (char*)d_ws;
    size_t off = 0;
    auto take = [&](size_t bytes) { char* p = base + off; off += (bytes + 255) & ~(size_t)255; return p; };
    unsigned* sorted  = (unsigned*)take((size_t)e * 4);                   // 12.8 MB
    int*      table   = (int*)take((size_t)NTILE * nbkt * 4);             // 0.8 MB
    int*      tot     = (int*)take((size_t)MAXB * 4);
    int*      bkt_off = (int*)take((size_t)(MAXB + 1) * 4);
    unsigned* nsorted = (unsigned*)take((size_t)e * 4);                   // 12.8 MB
    int*      nodeoff = (int*)take((size_t)(nbkt * 256 + 64) * 4);        // 0.4 MB
    float*    dinv    = (float*)take((size_t)n * 4);
    float*    xp      = (float*)take((size_t)n * 8);
    float*    aggx    = (float*)take((size_t)n * 8);
    float*    gp      = (float*)take((size_t)n * 8);

    const int gn = (n + BLK - 1) / BLK;
    dim3 gagg(nbkt, 4);

    k_hist    <<<NTILE, BLK, 0, stream>>>(dst, table, e, ept, nbkt);
    k_scan_col<<<nbkt, NTILE, 0, stream>>>(table, tot, nbkt);
    k_scan_tot<<<1, MAXB, 0, stream>>>(tot, bkt_off, nbkt);
    k_scatter <<<NTILE, BLK, 0, stream>>>(src, dst, table, tot, bkt_off, sorted, e, ept, nbkt);
    k_bsort   <<<nbkt, 1024, 0, stream>>>(sorted, bkt_off, x, dinv, xp, nsorted, nodeoff, n);
    k_agg1    <<<gagg, BLK, 0, stream>>>(nsorted, nodeoff, xp, dinv, aggx, n);
    k_mlp     <<<gn, BLK, 0, stream>>>(aggx, dinv, W1, b1, W2, gp, n);
    k_agg2    <<<gagg, BLK, 0, stream>>>(nsorted, nodeoff, gp, dinv, b2, out, n);
}

// Round 12
// 157.788 us; speedup vs baseline: 1.6509x; 1.0233x over previous
//
#include <hip/hip_runtime.h>
#include <math.h>

// GCN 2-layer, algebraically fused:
//   agg_x[d] = dinv[d]*(sum_{s in N(d)} xp[s] + xp[d]),  xp = dinv*x
//   h = relu(agg_x@W1+b1); g = h@W2; gp = dinv*g
//   out = log_softmax(dinv[d]*(sum gp[s] + gp[d]) + b2)
//
// R10 (161.5us): two-level counting sort -> node-contiguous records; atomic-
// free segmented-sum aggregation (4 lanes/node, shfl_xor quad reduce).
// R11: per-record issue reduction. (a) agg1/agg2 read records as ALIGNED
//      uint4 (segment aligned down to quad boundary, guarded edge quads) —
//      4x fewer record loads, 4 gathers in flight; (b) k_bsort both passes
//      uint4 with fast/slow path; (c) k_mlp fused into k_agg1 epilogue
//      (kills a dispatch + 1.6MB aggx round-trip). Fixed ~45-50us of the
//      measured total is harness fill (R9/R10 differential evidence).

#define BLK 256
#define NTILE 512
#define EPTMAX 6400        // >= runtime ept (6252), multiple of 4
#define MAXB 512           // >= nbkt = 391

// ---------- Phase A (unchanged from R5/R10) ----------

__global__ void k_hist(const int* __restrict__ dst, int* __restrict__ table,
                       int e, int ept, int nbkt) {
    __shared__ int h[MAXB];
    int tile = blockIdx.x;
    for (int i = threadIdx.x; i < MAXB; i += BLK) h[i] = 0;
    __syncthreads();
    int lo = tile * ept;
    int hi = min(lo + ept, e);
    for (int i = lo + 4 * threadIdx.x; i < hi; i += 4 * BLK) {
        int4 d4 = *(const int4*)(dst + i);
        atomicAdd(&h[d4.x >> 8], 1);
        atomicAdd(&h[d4.y >> 8], 1);
        atomicAdd(&h[d4.z >> 8], 1);
        atomicAdd(&h[d4.w >> 8], 1);
    }
    __syncthreads();
    for (int i = threadIdx.x; i < nbkt; i += BLK)
        table[tile * nbkt + i] = h[i];
}

__global__ void k_scan_col(int* __restrict__ table, int* __restrict__ tot, int nbkt) {
    __shared__ int wsum[NTILE / 64];
    int b = blockIdx.x;
    int t = threadIdx.x;
    int v = table[t * nbkt + b];
    int x = v;
    int lane = t & 63;
#pragma unroll
    for (int ofs = 1; ofs < 64; ofs <<= 1) {
        int y = __shfl_up(x, ofs, 64);
        if (lane >= ofs) x += y;
    }
    if (lane == 63) wsum[t >> 6] = x;
    __syncthreads();
    if (t < NTILE / 64) {
        int s = wsum[t];
        int w = s;
#pragma unroll
        for (int ofs = 1; ofs < NTILE / 64; ofs <<= 1) {
            int y = __shfl_up(w, ofs, 64);
            if (t >= ofs) w += y;
        }
        wsum[t] = w - s;
    }
    __syncthreads();
    int incl = x + wsum[t >> 6];
    table[t * nbkt + b] = incl - v;
    if (t == NTILE - 1) tot[b] = incl;
}

__global__ void k_scan_tot(const int* __restrict__ tot, int* __restrict__ bkt_off, int nbkt) {
    __shared__ int wsum[MAXB / 64];
    int t = threadIdx.x;               // MAXB threads
    int v = (t < nbkt) ? tot[t] : 0;
    int x = v;
    int lane = t & 63;
#pragma unroll
    for (int ofs = 1; ofs < 64; ofs <<= 1) {
        int y = __shfl_up(x, ofs, 64);
        if (lane >= ofs) x += y;
    }
    if (lane == 63) wsum[t >> 6] = x;
    __syncthreads();
    if (t < MAXB / 64) {
        int s = wsum[t];
        int w = s;
#pragma unroll
        for (int ofs = 1; ofs < MAXB / 64; ofs <<= 1) {
            int y = __shfl_up(w, ofs, 64);
            if (t >= ofs) w += y;
        }
        wsum[t] = w - s;
    }
    __syncthreads();
    int incl = x + wsum[t >> 6];
    if (t < nbkt) bkt_off[t] = incl - v;
    if (t == nbkt - 1) bkt_off[nbkt] = incl;
}

__global__ void k_scatter(const int* __restrict__ src, const int* __restrict__ dst,
                          const int* __restrict__ table, const int* __restrict__ tot,
                          const int* __restrict__ bkt_off, unsigned* __restrict__ sorted,
                          int e, int ept, int nbkt) {
    __shared__ int cur[MAXB];
    __shared__ int base2[MAXB];
    __shared__ unsigned stage[EPTMAX];
    __shared__ unsigned short stage_b[EPTMAX];
    __shared__ int wpart[BLK / 64];
    int tile = blockIdx.x;
    int t = threadIdx.x;
    int lo = tile * ept;
    int hi = min(lo + ept, e);
    int total = hi - lo;

    int b0 = 2 * t, b1 = 2 * t + 1;
    int c0 = 0, c1 = 0, g0 = 0, g1 = 0;
    if (b0 < nbkt) {
        int base = table[tile * nbkt + b0];
        int next = (tile < NTILE - 1) ? table[(tile + 1) * nbkt + b0] : tot[b0];
        c0 = next - base;
        g0 = bkt_off[b0] + base;
    }
    if (b1 < nbkt) {
        int base = table[tile * nbkt + b1];
        int next = (tile < NTILE - 1) ? table[(tile + 1) * nbkt + b1] : tot[b1];
        c1 = next - base;
        g1 = bkt_off[b1] + base;
    }
    int p = c0 + c1;
    int x = p;
    int lane = t & 63;
#pragma unroll
    for (int ofs = 1; ofs < 64; ofs <<= 1) {
        int y = __shfl_up(x, ofs, 64);
        if (lane >= ofs) x += y;
    }
    if (lane == 63) wpart[t >> 6] = x;
    __syncthreads();
    if (t < BLK / 64) {
        int s = wpart[t];
        int w = s;
#pragma unroll
        for (int ofs = 1; ofs < BLK / 64; ofs <<= 1) {
            int y = __shfl_up(w, ofs, 64);
            if (t >= ofs) w += y;
        }
        wpart[t] = w - s;
    }
    __syncthreads();
    int E = x + wpart[t >> 6] - p;
    cur[b0] = E;
    cur[b1] = E + c0;
    if (b0 < nbkt) base2[b0] = g0 - E;
    if (b1 < nbkt) base2[b1] = g1 - (E + c0);
    __syncthreads();

    for (int i = lo + 4 * t; i < hi; i += 4 * BLK) {
        int4 s4 = *(const int4*)(src + i);
        int4 d4 = *(const int4*)(dst + i);
        int b, pos;
        b = d4.x >> 8; pos = atomicAdd(&cur[b], 1);
        stage[pos] = (unsigned)s4.x | ((unsigned)(d4.x & 255) << 17); stage_b[pos] = (unsigned short)b;
        b = d4.y >> 8; pos = atomicAdd(&cur[b], 1);
        stage[pos] = (unsigned)s4.y | ((unsigned)(d4.y & 255) << 17); stage_b[pos] = (unsigned short)b;
        b = d4.z >> 8; pos = atomicAdd(&cur[b], 1);
        stage[pos] = (unsigned)s4.z | ((unsigned)(d4.z & 255) << 17); stage_b[pos] = (unsigned short)b;
        b = d4.w >> 8; pos = atomicAdd(&cur[b], 1);
        stage[pos] = (unsigned)s4.w | ((unsigned)(d4.w & 255) << 17); stage_b[pos] = (unsigned short)b;
    }
    __syncthreads();
    for (int j = t; j < total; j += BLK) {
        int b = stage_b[j];
        sorted[base2[b] + j] = stage[j];
    }
}

// ---------- per-bucket node-sort + degree + dinv + xp (uint4 passes) ----------
__global__ __launch_bounds__(1024) void k_bsort(
        const unsigned* __restrict__ sorted, const int* __restrict__ bkt_off,
        const float* __restrict__ x, float* __restrict__ dinv,
        float* __restrict__ xp, unsigned* __restrict__ nsorted,
        int* __restrict__ nodeoff, int n) {
    __shared__ int cnt[256];
    __shared__ int cur[256];
    __shared__ int wsum[16];
    int b = blockIdx.x, t = threadIdx.x;
    if (t < 256) cnt[t] = 0;
    __syncthreads();
    int lo = bkt_off[b], hi = bkt_off[b + 1];
    int la = lo & ~3;
    for (int i = la + 4 * t; i < hi; i += 4 * 1024) {
        uint4 r = *(const uint4*)(sorted + i);   // aligned; pad covers overread
        if (i >= lo && i + 4 <= hi) {
            atomicAdd(&cnt[r.x >> 17], 1);
            atomicAdd(&cnt[r.y >> 17], 1);
            atomicAdd(&cnt[r.z >> 17], 1);
            atomicAdd(&cnt[r.w >> 17], 1);
        } else {
            if (i + 0 >= lo && i + 0 < hi) atomicAdd(&cnt[r.x >> 17], 1);
            if (i + 1 >= lo && i + 1 < hi) atomicAdd(&cnt[r.y >> 17], 1);
            if (i + 2 >= lo && i + 2 < hi) atomicAdd(&cnt[r.z >> 17], 1);
            if (i + 3 >= lo && i + 3 < hi) atomicAdd(&cnt[r.w >> 17], 1);
        }
    }
    __syncthreads();
    int c = (t < 256) ? cnt[t] : 0;
    int node = (b << 8) + t;
    if (t < 256 && node < n) {
        float d = rsqrtf((float)c + 1.0f);   // +1 self loop
        dinv[node] = d;
        float2 xv = ((const float2*)x)[node];
        ((float2*)xp)[node] = make_float2(d * xv.x, d * xv.y);
    }
    int xsc = c;
    int lane = t & 63;
#pragma unroll
    for (int ofs = 1; ofs < 64; ofs <<= 1) {
        int y = __shfl_up(xsc, ofs, 64);
        if (lane >= ofs) xsc += y;
    }
    if (lane == 63) wsum[t >> 6] = xsc;
    __syncthreads();
    if (t < 4) {
        int s = wsum[t];
        int w = s;
#pragma unroll
        for (int ofs = 1; ofs < 4; ofs <<= 1) {
            int y = __shfl_up(w, ofs, 64);
            if (t >= ofs) w += y;
        }
        wsum[t] = w - s;
    }
    __syncthreads();
    if (t < 256) {
        int excl = xsc + wsum[t >> 6] - c;
        cur[t] = excl;
        nodeoff[(b << 8) + t] = lo + excl;
    }
    __syncthreads();
    for (int i = la + 4 * t; i < hi; i += 4 * 1024) {
        uint4 r = *(const uint4*)(sorted + i);
        if (i >= lo && i + 4 <= hi) {
            int p0 = atomicAdd(&cur[r.x >> 17], 1); nsorted[lo + p0] = r.x & 0x1FFFFu;
            int p1 = atomicAdd(&cur[r.y >> 17], 1); nsorted[lo + p1] = r.y & 0x1FFFFu;
            int p2 = atomicAdd(&cur[r.z >> 17], 1); nsorted[lo + p2] = r.z & 0x1FFFFu;
            int p3 = atomicAdd(&cur[r.w >> 17], 1); nsorted[lo + p3] = r.w & 0x1FFFFu;
        } else {
            if (i + 0 >= lo && i + 0 < hi) { int p0 = atomicAdd(&cur[r.x >> 17], 1); nsorted[lo + p0] = r.x & 0x1FFFFu; }
            if (i + 1 >= lo && i + 1 < hi) { int p1 = atomicAdd(&cur[r.y >> 17], 1); nsorted[lo + p1] = r.y & 0x1FFFFu; }
            if (i + 2 >= lo && i + 2 < hi) { int p2 = atomicAdd(&cur[r.z >> 17], 1); nsorted[lo + p2] = r.z & 0x1FFFFu; }
            if (i + 3 >= lo && i + 3 < hi) { int p3 = atomicAdd(&cur[r.w >> 17], 1); nsorted[lo + p3] = r.w & 0x1FFFFu; }
        }
    }
}

// ---------- Phase B: segmented sums, aligned uint4 record loads ----------

// layer 1 + fused MLP: gp[d] = dinv[d]*(relu(aggx@W1+b1)@W2)
__global__ void k_agg1(const unsigned* __restrict__ nsorted, const int* __restrict__ nodeoff,
                       const float* __restrict__ xp, const float* __restrict__ dinv,
                       const float* __restrict__ W1, const float* __restrict__ b1,
                       const float* __restrict__ W2, float* __restrict__ gp, int n) {
    int t = threadIdx.x;
    int nd = (blockIdx.x << 8) + (blockIdx.y << 6) + (t >> 2);
    int q = t & 3;
    if (nd >= n) return;
    int start = nodeoff[nd], end = nodeoff[nd + 1];
    const float2* xp2 = (const float2*)xp;
    float sx = 0.f, sy = 0.f;
    for (int p = (start & ~3) + 4 * q; p < end; p += 16) {
        uint4 r = *(const uint4*)(nsorted + p);   // aligned; pad covers overread
        if (p >= start && p + 4 <= end) {
            float2 f0 = xp2[r.x], f1 = xp2[r.y], f2 = xp2[r.z], f3 = xp2[r.w];
            sx += (f0.x + f1.x) + (f2.x + f3.x);
            sy += (f0.y + f1.y) + (f2.y + f3.y);
        } else {
            if (p + 0 >= start && p + 0 < end) { float2 f = xp2[r.x]; sx += f.x; sy += f.y; }
            if (p + 1 >= start && p + 1 < end) { float2 f = xp2[r.y]; sx += f.x; sy += f.y; }
            if (p + 2 >= start && p + 2 < end) { float2 f = xp2[r.z]; sx += f.x; sy += f.y; }
            if (p + 3 >= start && p + 3 < end) { float2 f = xp2[r.w]; sx += f.x; sy += f.y; }
        }
    }
    sx += __shfl_xor(sx, 1); sy += __shfl_xor(sy, 1);
    sx += __shfl_xor(sx, 2); sy += __shfl_xor(sy, 2);
    if (q == 0) {
        float d = dinv[nd];
        float2 xv = xp2[nd];
        float ax = d * (sx + xv.x), ay = d * (sy + xv.y);
        float g0 = 0.f, g1 = 0.f;
#pragma unroll
        for (int f = 0; f < 16; ++f) {
            float h = fmaf(ax, W1[f], fmaf(ay, W1[16 + f], b1[f]));
            h = fmaxf(h, 0.0f);
            g0 = fmaf(h, W2[2 * f + 0], g0);
            g1 = fmaf(h, W2[2 * f + 1], g1);
        }
        ((float2*)gp)[nd] = make_float2(d * g0, d * g1);
    }
}

// layer 2 + bias + log_softmax
__global__ void k_agg2(const unsigned* __restrict__ nsorted, const int* __restrict__ nodeoff,
                       const float* __restrict__ gp, const float* __restrict__ dinv,
                       const float* __restrict__ b2, float* __restrict__ out, int n) {
    int t = threadIdx.x;
    int nd = (blockIdx.x << 8) + (blockIdx.y << 6) + (t >> 2);
    int q = t & 3;
    if (nd >= n) return;
    int start = nodeoff[nd], end = nodeoff[nd + 1];
    const float2* gp2 = (const float2*)gp;
    float sx = 0.f, sy = 0.f;
    for (int p = (start & ~3) + 4 * q; p < end; p += 16) {
        uint4 r = *(const uint4*)(nsorted + p);
        if (p >= start && p + 4 <= end) {
            float2 f0 = gp2[r.x], f1 = gp2[r.y], f2 = gp2[r.z], f3 = gp2[r.w];
            sx += (f0.x + f1.x) + (f2.x + f3.x);
            sy += (f0.y + f1.y) + (f2.y + f3.y);
        } else {
            if (p + 0 >= start && p + 0 < end) { float2 f = gp2[r.x]; sx += f.x; sy += f.y; }
            if (p + 1 >= start && p + 1 < end) { float2 f = gp2[r.y]; sx += f.x; sy += f.y; }
            if (p + 2 >= start && p + 2 < end) { float2 f = gp2[r.z]; sx += f.x; sy += f.y; }
            if (p + 3 >= start && p + 3 < end) { float2 f = gp2[r.w]; sx += f.x; sy += f.y; }
        }
    }
    sx += __shfl_xor(sx, 1); sy += __shfl_xor(sy, 1);
    sx += __shfl_xor(sx, 2); sy += __shfl_xor(sy, 2);
    if (q == 0) {
        float d = dinv[nd];
        float2 gv = gp2[nd];
        float z0 = d * (sx + gv.x) + b2[0];
        float z1 = d * (sy + gv.y) + b2[1];
        float m = fmaxf(z0, z1);
        float lse = m + logf(expf(z0 - m) + expf(z1 - m));
        ((float2*)out)[nd] = make_float2(z0 - lse, z1 - lse);
    }
}

extern "C" void kernel_launch(void* const* d_in, const int* in_sizes, int n_in,
                              void* d_out, int out_size, void* d_ws, size_t ws_size,
                              hipStream_t stream) {
    const float* x  = (const float*)d_in[0];   // [n,2]
    const int*   ei = (const int*)d_in[1];     // [2,e]: row0=src, row1=dst
    const float* W1 = (const float*)d_in[2];   // [2,16]
    const float* b1 = (const float*)d_in[3];   // [16]
    const float* W2 = (const float*)d_in[4];   // [16,2]
    const float* b2 = (const float*)d_in[5];   // [2]
    float* out = (float*)d_out;                // [n,2]

    const int n = in_sizes[0] / 2;             // 100000
    const int e = in_sizes[1] / 2;             // 3200000
    const int* src = ei;
    const int* dst = ei + e;

    const int nbkt = (n + 255) >> 8;           // 391
    int ept = (((e + NTILE - 1) / NTILE) + 3) & ~3;   // 6252

    char* base = (char*)d_ws;
    size_t off = 0;
    auto take = [&](size_t bytes) { char* p = base + off; off += (bytes + 255) & ~(size_t)255; return p; };
    unsigned* sorted  = (unsigned*)take(((size_t)e + 8) * 4);             // 12.8 MB (+pad)
    int*      table   = (int*)take((size_t)NTILE * nbkt * 4);             // 0.8 MB
    int*      tot     = (int*)take((size_t)MAXB * 4);
    int*      bkt_off = (int*)take((size_t)(MAXB + 1) * 4);
    unsigned* nsorted = (unsigned*)take(((size_t)e + 8) * 4);             // 12.8 MB (+pad)
    int*      nodeoff = (int*)take((size_t)(nbkt * 256 + 64) * 4);        // 0.4 MB
    float*    dinv    = (float*)take((size_t)n * 4);
    float*    xp      = (float*)take((size_t)n * 8);
    float*    gp      = (float*)take((size_t)n * 8);

    dim3 gagg(nbkt, 4);

    k_hist    <<<NTILE, BLK, 0, stream>>>(dst, table, e, ept, nbkt);
    k_scan_col<<<nbkt, NTILE, 0, stream>>>(table, tot, nbkt);
    k_scan_tot<<<1, MAXB, 0, stream>>>(tot, bkt_off, nbkt);
    k_scatter <<<NTILE, BLK, 0, stream>>>(src, dst, table, tot, bkt_off, sorted, e, ept, nbkt);
    k_bsort   <<<nbkt, 1024, 0, stream>>>(sorted, bkt_off, x, dinv, xp, nsorted, nodeoff, n);
    k_agg1    <<<gagg, BLK, 0, stream>>>(nsorted, nodeoff, xp, dinv, W1, b1, W2, gp, n);
    k_agg2    <<<gagg, BLK, 0, stream>>>(nsorted, nodeoff, gp, dinv, b2, out, n);
}